// Round 7
// baseline (283.834 us; speedup 1.0000x reference)
//
#include <hip/hip_runtime.h>

// Problem constants (from reference)
constexpr int NSAMP  = 2048;
constexpr int NDIM   = 3072;   // H*W*C = 32*32*3
constexpr int NTRANS = 3072;   // NKERNEL*NCOMP = 192*16
constexpr int NBIN   = 200;
constexpr int NCLASS = 10;
constexpr int NPATCH = 192;
constexpr int BLK    = 256;
constexpr int PER_T  = NDIM / BLK;  // 12
constexpr int DSTR   = 20;          // s_diff row stride: 16B-aligned

// xb layout: one 64B line per (p, sl), physically swizzled to break the
// 128KB power-of-2 stride (channel camping): phys_sl = sl ^ (p & 63).
__device__ __forceinline__ float4* xb_line(float* xb, int p, int sl) {
    return (float4*)(xb + ((size_t)p * NSAMP + (sl ^ (p & 63))) * 16);
}
__device__ __forceinline__ const float4* xb_line_c(const float* xb, int p, int sl) {
    return (const float4*)(xb + ((size_t)p * NSAMP + (sl ^ (p & 63))) * 16);
}

// ---------------- P0: class bucketing (ballot) + Bt transpose ----------
__global__ __launch_bounds__(1024)
void p0_prep(const int* __restrict__ label,
             const float* __restrict__ B,
             int* __restrict__ slot,      // (NSAMP)
             int* __restrict__ cls_off,   // (NCLASS+1)
             float* __restrict__ Bt)      // (192,16,16): Bt[p][c][i]=B[p][i][c]
{
    __shared__ int s_lab[NSAMP];
    __shared__ int s_cnt[32][NCLASS];
    __shared__ int s_pre[32][NCLASS];
    __shared__ int s_tot[NCLASS];
    __shared__ int s_off[NCLASS + 1];
    const int tid  = threadIdx.x;
    const int lane = tid & 63;
    const int wv   = tid >> 6;

    for (int i = tid; i < NSAMP; i += 1024) s_lab[i] = label[i];
    // Bt transpose: 49152 elements, 48 per thread
    for (int e = tid; e < NPATCH * 256; e += 1024) {
        const int p = e >> 8, r = e & 255;          // r = i*16 + c
        Bt[p * 256 + (r & 15) * 16 + (r >> 4)] = B[e];
    }
    __syncthreads();

    const unsigned long long ltmask = ((unsigned long long)1 << lane) - 1;
    int myrank[2], myc[2];
    #pragma unroll
    for (int pass = 0; pass < 2; ++pass) {
        const int n = pass * 1024 + tid;
        const int c = s_lab[n];
        myc[pass] = c;
        int r = 0;
        #pragma unroll
        for (int cls = 0; cls < NCLASS; ++cls) {
            const unsigned long long b = __ballot(c == cls);
            if (lane == 0) s_cnt[pass * 16 + wv][cls] = __popcll(b);
            if (cls == c)  r = __popcll(b & ltmask);
        }
        myrank[pass] = r;
    }
    __syncthreads();

    if (tid < 32 * NCLASS) {
        const int seg = tid & 31;
        const int cls = tid >> 5;
        int acc = 0;
        for (int s = 0; s < seg; ++s) acc += s_cnt[s][cls];
        s_pre[seg][cls] = acc;
        if (seg == 31) s_tot[cls] = acc + s_cnt[31][cls];
    }
    __syncthreads();
    if (tid == 0) {
        int a = 0;
        for (int c = 0; c < NCLASS; ++c) { s_off[c] = a; a += s_tot[c]; }
        s_off[NCLASS] = a;
    }
    __syncthreads();

    #pragma unroll
    for (int pass = 0; pass < 2; ++pass) {
        const int n   = pass * 1024 + tid;
        const int seg = pass * 16 + wv;
        const int c   = myc[pass];
        slot[n] = s_off[c] + s_pre[seg][c] + myrank[pass];
    }
    if (tid <= NCLASS) cls_off[tid] = s_off[tid];
}

// ---------------- A: x = data @ wT -> blocked+swizzled layout ----------
__global__ __launch_bounds__(BLK)
void pA_project(const float* __restrict__ data,  // (N, NDIM)
                const float* __restrict__ Bt,    // (192,16,16) transposed
                const int*   __restrict__ slot,
                float* __restrict__ xb)
{
    __shared__ float s_data[NDIM];
    const int n = blockIdx.x;
    const int tid = threadIdx.x;

    const float* drow = data + (size_t)n * NDIM;
    #pragma unroll
    for (int j = 0; j < PER_T; ++j)
        s_data[tid + BLK * j] = drow[tid + BLK * j];
    __syncthreads();

    const int sl = slot[n];

    #pragma unroll
    for (int jj = 0; jj < 3; ++jj) {
        const int tau = tid + BLK * jj;     // 0..767 = p*4 + q4
        const int p   = tau >> 2;
        const int q4  = tau & 3;
        const int nh  = p / 24;
        const int rem = p - nh * 24;
        const int nw  = rem / 3;
        const int ch  = rem - nw * 3;
        const int rowbase = nh * 384 + nw * 12 + ch;

        float dv[16];
        #pragma unroll
        for (int i = 0; i < 16; ++i)
            dv[i] = s_data[rowbase + (i >> 2) * 96 + (i & 3) * 3];

        const float4* Bp = (const float4*)(Bt + p * 256 + q4 * 64);
        float acc[4];
        #pragma unroll
        for (int cc = 0; cc < 4; ++cc) {
            float a = 0.f;
            #pragma unroll
            for (int q = 0; q < 4; ++q) {
                const float4 b = Bp[cc * 4 + q];
                a += b.x * dv[q * 4 + 0] + b.y * dv[q * 4 + 1]
                   + b.z * dv[q * 4 + 2] + b.w * dv[q * 4 + 3];
            }
            acc[cc] = a;
        }
        *(xb_line(xb, p, sl) + q4) = make_float4(acc[0], acc[1], acc[2], acc[3]);
    }
}

// ---------------- B: spline, thread = (sample, coord-quad) ----------------
__global__ __launch_bounds__(BLK, 8)
void pB_spline(const float* __restrict__ kx,   // (10, NTRANS, NBIN)
               const float* __restrict__ ky,
               const float* __restrict__ kd,
               const int*   __restrict__ cls_off,
               float* __restrict__ xb,          // in: x, out: diff (in place)
               float* __restrict__ ljpart)      // (NPATCH, NSAMP)
{
    __shared__ float s_kx[16 * NBIN];           // 12.8 KB

    const int p   = blockIdx.x;   // 0..191
    const int c   = blockIdx.y;   // 0..9
    const int tid = threadIdx.x;
    const int t0  = p * 16;

    const size_t kofs = ((size_t)c * NTRANS + t0) * NBIN;
    const float4* gx = (const float4*)(kx + kofs);
    float4* lx = (float4*)s_kx;
    #pragma unroll 1
    for (int i = tid; i < 16 * NBIN / 4; i += BLK) lx[i] = gx[i];
    __syncthreads();

    const int qq  = tid & 3;      // coord quad
    const int sid = tid >> 2;     // 0..63 sample within pass
    const float* sxx = s_kx + qq * 4 * NBIN;
    const float* kyp = ky + kofs + (size_t)(qq * 4) * NBIN;
    const float* kdp = kd + kofs + (size_t)(qq * 4) * NBIN;

    const int beg = cls_off[c];
    const int end = cls_off[c + 1];

    for (int s0 = beg; s0 < end; s0 += 64) {
        const int sl = s0 + sid;            // quad-uniform
        if (sl < end) {
            float4* line = xb_line(xb, p, sl) + qq;
            const float4 v = *line;
            float xs[4] = {v.x, v.y, v.z, v.w};

            float lj_sum = 0.f;
            #pragma unroll
            for (int j = 0; j < 4; ++j) {
                const float* xx  = sxx + j * NBIN;
                const float* yyg = kyp + j * NBIN;
                const float* ddg = kdp + j * NBIN;
                const float x  = xs[j];
                const float lo = xx[0];
                const float hi = xx[NBIN - 1];

                float y, lj;
                if (x < lo) {
                    const float d0 = ddg[0];
                    y  = yyg[0] + (x - lo) * d0;
                    lj = __logf(d0);
                } else if (x > hi) {
                    const float dK = ddg[NBIN - 1];
                    y  = yyg[NBIN - 1] + (x - hi) * dK;
                    lj = __logf(dK);
                } else {
                    int klo = 0, khi = NBIN;
                    #pragma unroll
                    for (int it = 0; it < 8; ++it) {
                        const int mid = (klo + khi) >> 1;
                        const bool le = (xx[mid] <= x);
                        klo = le ? mid : klo;
                        khi = le ? khi : mid;
                    }
                    int k = klo;
                    if (k > NBIN - 2) k = NBIN - 2;

                    const float xk = xx[k], xk1 = xx[k + 1];
                    const float yk = yyg[k], yk1 = yyg[k + 1];
                    const float dk = ddg[k], dk1 = ddg[k + 1];

                    const float wdt     = xk1 - xk;
                    const float inv_wdt = __fdividef(1.f, wdt);
                    const float dy      = yk1 - yk;
                    const float s       = dy * inv_wdt;
                    const float xi      = (x - xk) * inv_wdt;
                    const float om      = 1.f - xi;
                    const float denom   = s + (dk1 + dk - 2.f * s) * xi * om;
                    const float r       = __fdividef(1.f, denom);
                    const float num     = dy * (s * xi * xi + dk * xi * om);
                    y = yk + num * r;
                    const float Nq = dk1 * xi * xi + 2.f * s * xi * om + dk * om * om;
                    const float t2 = s * r;
                    lj = __logf(t2 * t2 * Nq);
                }
                xs[j] = y - x;
                lj_sum += lj;
            }

            *line = make_float4(xs[0], xs[1], xs[2], xs[3]);

            lj_sum += __shfl_xor(lj_sum, 1);
            lj_sum += __shfl_xor(lj_sum, 2);
            if (qq == 0) ljpart[(size_t)p * NSAMP + sl] = lj_sum;
        }
    }
}

// ---------------- ljreduce: logj_slot[sl] = sum_p ljpart[p][sl] ------------
__global__ __launch_bounds__(BLK)
void p_ljred(const float* __restrict__ ljpart,
             float* __restrict__ logj_slot)
{
    const int sl = blockIdx.x * BLK + threadIdx.x;
    float a0 = 0.f, a1 = 0.f, a2 = 0.f, a3 = 0.f;
    #pragma unroll 1
    for (int g = 0; g < NPATCH; g += 4) {
        a0 += ljpart[(size_t)(g + 0) * NSAMP + sl];
        a1 += ljpart[(size_t)(g + 1) * NSAMP + sl];
        a2 += ljpart[(size_t)(g + 2) * NSAMP + sl];
        a3 += ljpart[(size_t)(g + 3) * NSAMP + sl];
    }
    logj_slot[sl] = (a0 + a1) + (a2 + a3);
}

// ---------------- C: out = data + diff @ wT^T ----------------
__global__ __launch_bounds__(BLK)
void pC_recon(const float* __restrict__ data,
              const float* __restrict__ B,
              const int*   __restrict__ slot,
              const float* __restrict__ xb,        // diff, blocked+swizzled
              const float* __restrict__ logj_slot,
              float* __restrict__ out,
              float* __restrict__ logj)
{
    __shared__ float s_diff[NPATCH * DSTR];   // 15.4 KB
    const int n   = blockIdx.x;
    const int tid = threadIdx.x;
    const int sl  = slot[n];

    #pragma unroll
    for (int jj = 0; jj < 3; ++jj) {
        const int i  = tid + BLK * jj;      // 0..767 = pp*4 + q
        const int pp = i >> 2;
        const int q  = i & 3;
        const float4 v = *(xb_line_c(xb, pp, sl) + q);
        *(float4*)&s_diff[pp * DSTR + q * 4] = v;
    }
    if (tid == 0) logj[n] = logj_slot[sl];
    __syncthreads();

    const float* drow = data + (size_t)n * NDIM;
    float* orow = out + (size_t)n * NDIM;
    #pragma unroll 1
    for (int j = 0; j < PER_T; ++j) {
        const int d  = tid + BLK * j;
        const int ch = d % 3;
        const int hw = d / 3;
        const int w  = hw & 31;
        const int h  = hw >> 5;
        const int p  = ((h >> 2) * 8 + (w >> 2)) * 3 + ch;
        const int i  = (h & 3) * 4 + (w & 3);

        const float4* Bp4 = (const float4*)(B + p * 256 + i * 16);
        const float4* dp4 = (const float4*)&s_diff[p * DSTR];
        float acc = drow[d];
        #pragma unroll
        for (int q = 0; q < 4; ++q) {
            const float4 b = Bp4[q];
            const float4 dd = dp4[q];
            acc += b.x * dd.x + b.y * dd.y + b.z * dd.z + b.w * dd.w;
        }
        orow[d] = acc;
    }
}

extern "C" void kernel_launch(void* const* d_in, const int* in_sizes, int n_in,
                              void* d_out, int out_size, void* d_ws, size_t ws_size,
                              hipStream_t stream) {
    const float* data  = (const float*)d_in[0];
    const int*   label = (const int*)  d_in[1];
    const float* B     = (const float*)d_in[2];
    const float* kx    = (const float*)d_in[3];
    const float* ky    = (const float*)d_in[4];
    const float* kd    = (const float*)d_in[5];

    float* out  = (float*)d_out;
    float* logj = (float*)d_out + (size_t)NSAMP * NDIM;

    // ws layout
    char* ws = (char*)d_ws;
    size_t off = 0;
    float* xb        = (float*)(ws + off); off += (size_t)NPATCH * NSAMP * 16 * 4; // 25.2 MB
    float* ljpart    = (float*)(ws + off); off += (size_t)NPATCH * NSAMP * 4;      // 1.6 MB
    float* Bt        = (float*)(ws + off); off += (size_t)NPATCH * 256 * 4;        // 196 KB
    float* logj_slot = (float*)(ws + off); off += NSAMP * 4;
    int*   slot      = (int*)  (ws + off); off += NSAMP * 4;
    int*   cls_off   = (int*)  (ws + off); off += 64;

    p0_prep   <<<1, 1024, 0, stream>>>(label, B, slot, cls_off, Bt);
    pA_project<<<NSAMP, BLK, 0, stream>>>(data, Bt, slot, xb);
    dim3 gridB(NPATCH, NCLASS);
    pB_spline <<<gridB, BLK, 0, stream>>>(kx, ky, kd, cls_off, xb, ljpart);
    p_ljred   <<<NSAMP / BLK, BLK, 0, stream>>>(ljpart, logj_slot);
    pC_recon  <<<NSAMP, BLK, 0, stream>>>(data, B, slot, xb, logj_slot, out, logj);
}

// Round 8
// 237.735 us; speedup vs baseline: 1.1939x; 1.1939x over previous
//
#include <hip/hip_runtime.h>

// Problem constants (from reference)
constexpr int NSAMP  = 2048;
constexpr int NDIM   = 3072;   // H*W*C = 32*32*3
constexpr int NTRANS = 3072;   // NKERNEL*NCOMP = 192*16
constexpr int NBIN   = 200;
constexpr int NCLASS = 10;
constexpr int NPATCH = 192;
constexpr int BLK    = 256;
constexpr int PER_T  = NDIM / BLK;  // 12
constexpr int DSTR   = 20;          // s_diff row stride: 16B-aligned
constexpr int SA     = 4;           // samples per pA block (B reg-amortization)
constexpr int SC     = 4;           // samples per pC block

// xb layout: one 64B line per (p, sl); phys_sl swizzle kept (neutral).
__device__ __forceinline__ float4* xb_line(float* xb, int p, int sl) {
    return (float4*)(xb + ((size_t)p * NSAMP + (sl ^ (p & 63))) * 16);
}
__device__ __forceinline__ const float4* xb_line_c(const float* xb, int p, int sl) {
    return (const float4*)(xb + ((size_t)p * NSAMP + (sl ^ (p & 63))) * 16);
}

// ---------------- P0: class bucketing (ballot) + Bt transpose ----------
__global__ __launch_bounds__(1024)
void p0_prep(const int* __restrict__ label,
             const float* __restrict__ B,
             int* __restrict__ slot,      // (NSAMP)
             int* __restrict__ cls_off,   // (NCLASS+1)
             float* __restrict__ Bt)      // Bt[p][c][i] = B[p][i][c]
{
    __shared__ int s_lab[NSAMP];
    __shared__ int s_cnt[32][NCLASS];
    __shared__ int s_pre[32][NCLASS];
    __shared__ int s_tot[NCLASS];
    __shared__ int s_off[NCLASS + 1];
    const int tid  = threadIdx.x;
    const int lane = tid & 63;
    const int wv   = tid >> 6;

    for (int i = tid; i < NSAMP; i += 1024) s_lab[i] = label[i];
    for (int e = tid; e < NPATCH * 256; e += 1024) {
        const int p = e >> 8, r = e & 255;          // r = i*16 + c
        Bt[p * 256 + (r & 15) * 16 + (r >> 4)] = B[e];
    }
    __syncthreads();

    const unsigned long long ltmask = ((unsigned long long)1 << lane) - 1;
    int myrank[2], myc[2];
    #pragma unroll
    for (int pass = 0; pass < 2; ++pass) {
        const int n = pass * 1024 + tid;
        const int c = s_lab[n];
        myc[pass] = c;
        int r = 0;
        #pragma unroll
        for (int cls = 0; cls < NCLASS; ++cls) {
            const unsigned long long b = __ballot(c == cls);
            if (lane == 0) s_cnt[pass * 16 + wv][cls] = __popcll(b);
            if (cls == c)  r = __popcll(b & ltmask);
        }
        myrank[pass] = r;
    }
    __syncthreads();

    if (tid < 32 * NCLASS) {
        const int seg = tid & 31;
        const int cls = tid >> 5;
        int acc = 0;
        for (int s = 0; s < seg; ++s) acc += s_cnt[s][cls];
        s_pre[seg][cls] = acc;
        if (seg == 31) s_tot[cls] = acc + s_cnt[31][cls];
    }
    __syncthreads();
    if (tid == 0) {
        int a = 0;
        for (int c = 0; c < NCLASS; ++c) { s_off[c] = a; a += s_tot[c]; }
        s_off[NCLASS] = a;
    }
    __syncthreads();

    #pragma unroll
    for (int pass = 0; pass < 2; ++pass) {
        const int n   = pass * 1024 + tid;
        const int seg = pass * 16 + wv;
        const int c   = myc[pass];
        slot[n] = s_off[c] + s_pre[seg][c] + myrank[pass];
    }
    if (tid <= NCLASS) cls_off[tid] = s_off[tid];
}

// ---------------- A: x = data @ wT, SA samples/block ----------------
// Thread = (patch, c-quad); Bt fragment (16 float4) loaded to regs ONCE,
// reused for SA samples -> 4x fewer B line-requests through L1.
__global__ __launch_bounds__(BLK, 4)
void pA_project(const float* __restrict__ data,  // (N, NDIM)
                const float* __restrict__ Bt,    // (192,16,16) transposed
                const int*   __restrict__ slot,
                float* __restrict__ xb)
{
    __shared__ float s_data[SA][NDIM];           // 48 KB
    const int b   = blockIdx.x;
    const int tid = threadIdx.x;
    const int n0  = b * SA;

    #pragma unroll
    for (int s = 0; s < SA; ++s) {
        const float4* dr = (const float4*)(data + (size_t)(n0 + s) * NDIM);
        float4* sd = (float4*)s_data[s];
        #pragma unroll
        for (int j = 0; j < 3; ++j)
            sd[tid + BLK * j] = dr[tid + BLK * j];
    }
    int sls[SA];
    #pragma unroll
    for (int s = 0; s < SA; ++s) sls[s] = slot[n0 + s];
    __syncthreads();

    #pragma unroll 1
    for (int jj = 0; jj < 3; ++jj) {
        const int tau = tid + BLK * jj;     // 0..767 = p*4 + q4
        const int p   = tau >> 2;
        const int q4  = tau & 3;
        const int nh  = p / 24;
        const int rem = p - nh * 24;
        const int nw  = rem / 3;
        const int ch  = rem - nw * 3;
        const int rowbase = nh * 384 + nw * 12 + ch;

        float4 Bp[16];
        const float4* Bg = (const float4*)(Bt + p * 256 + q4 * 64);
        #pragma unroll
        for (int i = 0; i < 16; ++i) Bp[i] = Bg[i];

        #pragma unroll
        for (int s = 0; s < SA; ++s) {
            float dv[16];
            #pragma unroll
            for (int i = 0; i < 16; ++i)
                dv[i] = s_data[s][rowbase + (i >> 2) * 96 + (i & 3) * 3];

            float acc[4];
            #pragma unroll
            for (int cc = 0; cc < 4; ++cc) {
                float a = 0.f;
                #pragma unroll
                for (int q = 0; q < 4; ++q) {
                    const float4 bv = Bp[cc * 4 + q];
                    a += bv.x * dv[q * 4 + 0] + bv.y * dv[q * 4 + 1]
                       + bv.z * dv[q * 4 + 2] + bv.w * dv[q * 4 + 3];
                }
                acc[cc] = a;
            }
            *(xb_line(xb, p, sls[s]) + q4) =
                make_float4(acc[0], acc[1], acc[2], acc[3]);
        }
    }
}

// ---------------- B: spline, thread = (sample, coord-quad) ----------------
__global__ __launch_bounds__(BLK, 8)
void pB_spline(const float* __restrict__ kx,   // (10, NTRANS, NBIN)
               const float* __restrict__ ky,
               const float* __restrict__ kd,
               const int*   __restrict__ cls_off,
               float* __restrict__ xb,          // in: x, out: diff (in place)
               float* __restrict__ ljpart)      // (NPATCH, NSAMP)
{
    __shared__ float s_kx[16 * NBIN];           // 12.8 KB

    const int p   = blockIdx.x;
    const int c   = blockIdx.y;
    const int tid = threadIdx.x;
    const int t0  = p * 16;

    const size_t kofs = ((size_t)c * NTRANS + t0) * NBIN;
    const float4* gx = (const float4*)(kx + kofs);
    float4* lx = (float4*)s_kx;
    #pragma unroll 1
    for (int i = tid; i < 16 * NBIN / 4; i += BLK) lx[i] = gx[i];
    __syncthreads();

    const int qq  = tid & 3;
    const int sid = tid >> 2;
    const float* sxx = s_kx + qq * 4 * NBIN;
    const float* kyp = ky + kofs + (size_t)(qq * 4) * NBIN;
    const float* kdp = kd + kofs + (size_t)(qq * 4) * NBIN;

    const int beg = cls_off[c];
    const int end = cls_off[c + 1];

    for (int s0 = beg; s0 < end; s0 += 64) {
        const int sl = s0 + sid;            // quad-uniform
        if (sl < end) {
            float4* line = xb_line(xb, p, sl) + qq;
            const float4 v = *line;
            float xs[4] = {v.x, v.y, v.z, v.w};

            float lj_sum = 0.f;
            #pragma unroll
            for (int j = 0; j < 4; ++j) {
                const float* xx  = sxx + j * NBIN;
                const float* yyg = kyp + j * NBIN;
                const float* ddg = kdp + j * NBIN;
                const float x  = xs[j];
                const float lo = xx[0];
                const float hi = xx[NBIN - 1];

                float y, lj;
                if (x < lo) {
                    const float d0 = ddg[0];
                    y  = yyg[0] + (x - lo) * d0;
                    lj = __logf(d0);
                } else if (x > hi) {
                    const float dK = ddg[NBIN - 1];
                    y  = yyg[NBIN - 1] + (x - hi) * dK;
                    lj = __logf(dK);
                } else {
                    int klo = 0, khi = NBIN;
                    #pragma unroll
                    for (int it = 0; it < 8; ++it) {
                        const int mid = (klo + khi) >> 1;
                        const bool le = (xx[mid] <= x);
                        klo = le ? mid : klo;
                        khi = le ? khi : mid;
                    }
                    int k = klo;
                    if (k > NBIN - 2) k = NBIN - 2;

                    const float xk = xx[k], xk1 = xx[k + 1];
                    const float yk = yyg[k], yk1 = yyg[k + 1];
                    const float dk = ddg[k], dk1 = ddg[k + 1];

                    const float wdt     = xk1 - xk;
                    const float inv_wdt = __fdividef(1.f, wdt);
                    const float dy      = yk1 - yk;
                    const float s       = dy * inv_wdt;
                    const float xi      = (x - xk) * inv_wdt;
                    const float om      = 1.f - xi;
                    const float denom   = s + (dk1 + dk - 2.f * s) * xi * om;
                    const float r       = __fdividef(1.f, denom);
                    const float num     = dy * (s * xi * xi + dk * xi * om);
                    y = yk + num * r;
                    const float Nq = dk1 * xi * xi + 2.f * s * xi * om + dk * om * om;
                    const float t2 = s * r;
                    lj = __logf(t2 * t2 * Nq);
                }
                xs[j] = y - x;
                lj_sum += lj;
            }

            *line = make_float4(xs[0], xs[1], xs[2], xs[3]);

            lj_sum += __shfl_xor(lj_sum, 1);
            lj_sum += __shfl_xor(lj_sum, 2);
            if (qq == 0) ljpart[(size_t)p * NSAMP + sl] = lj_sum;
        }
    }
}

// ---------------- ljreduce: logj_slot[sl] = sum_p ljpart[p][sl] ------------
__global__ __launch_bounds__(BLK)
void p_ljred(const float* __restrict__ ljpart,
             float* __restrict__ logj_slot)
{
    const int sl = blockIdx.x * BLK + threadIdx.x;
    float a0 = 0.f, a1 = 0.f, a2 = 0.f, a3 = 0.f;
    #pragma unroll 1
    for (int g = 0; g < NPATCH; g += 4) {
        a0 += ljpart[(size_t)(g + 0) * NSAMP + sl];
        a1 += ljpart[(size_t)(g + 1) * NSAMP + sl];
        a2 += ljpart[(size_t)(g + 2) * NSAMP + sl];
        a3 += ljpart[(size_t)(g + 3) * NSAMP + sl];
    }
    logj_slot[sl] = (a0 + a1) + (a2 + a3);
}

// ---------------- C: out = data + diff @ wT^T, SC samples/block ------------
// B row (4 float4) loaded once per output-dim task, reused for SC samples.
__global__ __launch_bounds__(BLK, 2)
void pC_recon(const float* __restrict__ data,
              const float* __restrict__ B,
              const int*   __restrict__ slot,
              const float* __restrict__ xb,        // diff, blocked layout
              const float* __restrict__ logj_slot,
              float* __restrict__ out,
              float* __restrict__ logj)
{
    __shared__ float s_diff[SC][NPATCH * DSTR];   // 61.4 KB
    const int b   = blockIdx.x;
    const int tid = threadIdx.x;
    const int n0  = b * SC;

    #pragma unroll
    for (int s = 0; s < SC; ++s) {
        const int sl = slot[n0 + s];
        #pragma unroll
        for (int jj = 0; jj < 3; ++jj) {
            const int i  = tid + BLK * jj;      // 0..767 = pp*4 + q
            const int pp = i >> 2;
            const int q  = i & 3;
            const float4 v = *(xb_line_c(xb, pp, sl) + q);
            *(float4*)&s_diff[s][pp * DSTR + q * 4] = v;
        }
    }
    if (tid < SC) logj[n0 + tid] = logj_slot[slot[n0 + tid]];
    __syncthreads();

    #pragma unroll 1
    for (int j = 0; j < PER_T; ++j) {
        const int d  = tid + BLK * j;
        const int ch = d % 3;
        const int hw = d / 3;
        const int w  = hw & 31;
        const int h  = hw >> 5;
        const int p  = ((h >> 2) * 8 + (w >> 2)) * 3 + ch;
        const int i  = (h & 3) * 4 + (w & 3);

        const float4* Bp4 = (const float4*)(B + p * 256 + i * 16);
        const float4 b0 = Bp4[0], b1 = Bp4[1], b2 = Bp4[2], b3 = Bp4[3];

        #pragma unroll
        for (int s = 0; s < SC; ++s) {
            const float4* dp4 = (const float4*)&s_diff[s][p * DSTR];
            const float4 d0 = dp4[0], d1 = dp4[1], d2 = dp4[2], d3 = dp4[3];
            float acc = data[(size_t)(n0 + s) * NDIM + d];
            acc += b0.x * d0.x + b0.y * d0.y + b0.z * d0.z + b0.w * d0.w;
            acc += b1.x * d1.x + b1.y * d1.y + b1.z * d1.z + b1.w * d1.w;
            acc += b2.x * d2.x + b2.y * d2.y + b2.z * d2.z + b2.w * d2.w;
            acc += b3.x * d3.x + b3.y * d3.y + b3.z * d3.z + b3.w * d3.w;
            out[(size_t)(n0 + s) * NDIM + d] = acc;
        }
    }
}

extern "C" void kernel_launch(void* const* d_in, const int* in_sizes, int n_in,
                              void* d_out, int out_size, void* d_ws, size_t ws_size,
                              hipStream_t stream) {
    const float* data  = (const float*)d_in[0];
    const int*   label = (const int*)  d_in[1];
    const float* B     = (const float*)d_in[2];
    const float* kx    = (const float*)d_in[3];
    const float* ky    = (const float*)d_in[4];
    const float* kd    = (const float*)d_in[5];

    float* out  = (float*)d_out;
    float* logj = (float*)d_out + (size_t)NSAMP * NDIM;

    // ws layout
    char* ws = (char*)d_ws;
    size_t off = 0;
    float* xb        = (float*)(ws + off); off += (size_t)NPATCH * NSAMP * 16 * 4; // 25.2 MB
    float* ljpart    = (float*)(ws + off); off += (size_t)NPATCH * NSAMP * 4;      // 1.6 MB
    float* Bt        = (float*)(ws + off); off += (size_t)NPATCH * 256 * 4;        // 196 KB
    float* logj_slot = (float*)(ws + off); off += NSAMP * 4;
    int*   slot      = (int*)  (ws + off); off += NSAMP * 4;
    int*   cls_off   = (int*)  (ws + off); off += 64;

    p0_prep   <<<1, 1024, 0, stream>>>(label, B, slot, cls_off, Bt);
    pA_project<<<NSAMP / SA, BLK, 0, stream>>>(data, Bt, slot, xb);
    dim3 gridB(NPATCH, NCLASS);
    pB_spline <<<gridB, BLK, 0, stream>>>(kx, ky, kd, cls_off, xb, ljpart);
    p_ljred   <<<NSAMP / BLK, BLK, 0, stream>>>(ljpart, logj_slot);
    pC_recon  <<<NSAMP / SC, BLK, 0, stream>>>(data, B, slot, xb, logj_slot, out, logj);
}